// Round 1
// baseline (490.947 us; speedup 1.0000x reference)
//
#include <hip/hip_runtime.h>

// Problem constants (from reference): [N,C,D,H,W] output, fp32.
constexpr int N = 2, C = 32, H = 128, W = 256, MAX_DISP = 48;
constexpr int W4 = W / 4;                                   // 64 float4 per row
constexpr int TOTAL4 = N * C * MAX_DISP * H * W4;           // 25,165,824 float4 stores

// cost[n,c,d,h,w] = (w >= d) ? l[n,c,h,w] - r[n,c,h,w-d] : 1.0f
__global__ __launch_bounds__(256) void cost_volume_kernel(
    const float* __restrict__ l,
    const float* __restrict__ r,
    float4* __restrict__ out)
{
    int idx = blockIdx.x * blockDim.x + threadIdx.x;   // < TOTAL4, fits in int32
    if (idx >= TOTAL4) return;

    // idx = (((nc)*D + d)*H + h)*W4 + w4, where nc = n*C + c
    int w4 = idx & (W4 - 1);          // W4 = 64, pow2
    int t  = idx >> 6;                // / W4
    int h  = t & (H - 1);             // H = 128, pow2
    t >>= 7;                          // / H
    int d  = t % MAX_DISP;
    int nc = t / MAX_DISP;

    int w0 = w4 << 2;                 // starting w of this float4
    const float* lrow = l + ((size_t)nc * H + h) * W;
    const float* rrow = r + ((size_t)nc * H + h) * W;

    // Aligned 16B load of l; predicated scalar loads of r (unaligned by d).
    float4 lv = *reinterpret_cast<const float4*>(lrow + w0);

    float4 o;
    o.x = (w0 + 0 >= d) ? lv.x - rrow[w0 + 0 - d] : 1.0f;
    o.y = (w0 + 1 >= d) ? lv.y - rrow[w0 + 1 - d] : 1.0f;
    o.z = (w0 + 2 >= d) ? lv.z - rrow[w0 + 2 - d] : 1.0f;
    o.w = (w0 + 3 >= d) ? lv.w - rrow[w0 + 3 - d] : 1.0f;

    out[idx] = o;                     // aligned 16B coalesced store
}

extern "C" void kernel_launch(void* const* d_in, const int* in_sizes, int n_in,
                              void* d_out, int out_size, void* d_ws, size_t ws_size,
                              hipStream_t stream)
{
    const float* l = (const float*)d_in[0];
    const float* r = (const float*)d_in[1];
    float4* out = (float4*)d_out;

    constexpr int BLOCK = 256;
    constexpr int GRID = (TOTAL4 + BLOCK - 1) / BLOCK;   // 98,304 blocks
    cost_volume_kernel<<<GRID, BLOCK, 0, stream>>>(l, r, out);
}

// Round 2
// 405.155 us; speedup vs baseline: 1.2118x; 1.2118x over previous
//
#include <hip/hip_runtime.h>

// [N,C,D,H,W] = [2,32,48,128,256] fp32 output (402.7 MB) — store-bandwidth-bound.
// cost[nc,d,h,w] = (w >= d) ? l[nc,h,w] - r[nc,h,w-d] : 1.0f
constexpr int N = 2, C = 32, H = 128, W = 256, D = 48;
constexpr int NC = N * C;     // 64
constexpr int W4 = W / 4;     // 64 float4 per row == wave width
constexpr int PASSES = D / 4; // 4 waves/block, each covers one d per pass

__global__ __launch_bounds__(256) void cost_volume_kernel(
    const float* __restrict__ l,
    const float* __restrict__ r,
    float4* __restrict__ out)
{
    // r row staged in LDS, front-padded by D so (w - d) never indexes negative.
    __shared__ float r_lds[D + W];

    const int blk = blockIdx.x;        // = nc*H + h, 8192 blocks
    const int h   = blk & (H - 1);
    const int nc  = blk >> 7;          // / H

    const float* lrow = l + (size_t)blk * W;
    const float* rrow = r + (size_t)blk * W;

    const int t = threadIdx.x;
    r_lds[D + t] = rrow[t];            // 256 threads, coalesced 1 KB fill
    if (t < D) r_lds[t] = 0.0f;        // pad (masked lanes read here, value discarded)

    const int lane = t & 63;           // w4 index == lane
    const int wv   = t >> 6;           // wave id 0..3
    const int w0   = lane << 2;

    // l float4 is invariant across d — load once (L1/L2 hit for waves 1-3).
    const float4 lv = *reinterpret_cast<const float4*>(lrow + w0);

    __syncthreads();

    // out float4 index for (nc, d, h, w4): ((nc*D + d)*H + h)*W4 + w4
    float4* obase = out + (((size_t)nc * D * H) + h) * W4 + lane;
    const size_t dstride = (size_t)H * W4;   // one disparity plane, in float4

    #pragma unroll
    for (int pass = 0; pass < PASSES; ++pass) {
        const int d = wv + pass * 4;         // wave-uniform disparity
        const float* rs = r_lds + (D - d) + w0;
        float4 o;
        o.x = (w0 + 0 >= d) ? lv.x - rs[0] : 1.0f;
        o.y = (w0 + 1 >= d) ? lv.y - rs[1] : 1.0f;
        o.z = (w0 + 2 >= d) ? lv.z - rs[2] : 1.0f;
        o.w = (w0 + 3 >= d) ? lv.w - rs[3] : 1.0f;
        obase[(size_t)d * dstride] = o;      // 64 lanes × 16 B = one contiguous 1 KB row
    }
}

extern "C" void kernel_launch(void* const* d_in, const int* in_sizes, int n_in,
                              void* d_out, int out_size, void* d_ws, size_t ws_size,
                              hipStream_t stream)
{
    const float* l = (const float*)d_in[0];
    const float* r = (const float*)d_in[1];
    float4* out = (float4*)d_out;

    constexpr int GRID = NC * H;   // 8192 blocks, 256 threads each
    cost_volume_kernel<<<GRID, 256, 0, stream>>>(l, r, out);
}